// Round 1
// baseline (8896.296 us; speedup 1.0000x reference)
//
#include <hip/hip_runtime.h>
#include <stdint.h>

#define T_LEN 512
#define NB 64
#define EMBD 256
#define HD 256
#define G4 1024
#define STOPID 30

typedef unsigned short u16;
typedef unsigned int u32;

__device__ __forceinline__ float bf_lo(u32 u){ return __uint_as_float(u << 16); }
__device__ __forceinline__ float bf_hi(u32 u){ return __uint_as_float(u & 0xFFFF0000u); }
__device__ __forceinline__ float bf2f(u16 v){ return __uint_as_float(((u32)v) << 16); }
__device__ __forceinline__ u16 f2bf(float f){
  u32 u = __float_as_uint(f);
  return (u16)((u + 0x7FFFu + ((u >> 16) & 1u)) >> 16);
}
__device__ __forceinline__ float sigm(float x){ return 1.0f/(1.0f + __expf(-x)); }
__device__ __forceinline__ float tanhfast(float x){ return 1.0f - 2.0f/(1.0f + __expf(2.0f*x)); }

// ---------------- K0: convert Whh_f / Whh_b to bf16 in ws ----------------
extern "C" __global__ __launch_bounds__(256) void k0_cvt(
    const float* __restrict__ wf, const float* __restrict__ wb, u16* __restrict__ out)
{
  int i = blockIdx.x * 256 + threadIdx.x;   // grid 1024 -> 262144 threads
  out[i]          = f2bf(wf[i]);
  out[262144 + i] = f2bf(wb[i]);
}

// ---------------- K1: xW[dir][t][b][1024] = emb[inp[b][t]] @ Wih_dir.T + b_dir ----------------
// grid (512 t-tiles, 32 n-tiles of 64), 256 threads, 64x64 tile, fp32
extern "C" __global__ __launch_bounds__(256) void k1_proj(
    const int* __restrict__ inp, const float* __restrict__ emb,
    const float* __restrict__ Wih_f, const float* __restrict__ Wih_b,
    const float* __restrict__ b_f, const float* __restrict__ b_b,
    u16* __restrict__ xW)
{
  __shared__ __align__(16) float As[32][68];   // [k][m], pad 68 -> 16B-aligned rows
  __shared__ __align__(16) float Bs[32][68];   // [k][n]
  __shared__ int tok[64];

  int t   = blockIdx.x;          // 0..511 (all 64 batch rows of one t per tile)
  int n0  = blockIdx.y * 64;     // 0..2047
  int dir = n0 >> 10;
  int wr0 = n0 & 1023;
  const float* W    = dir ? Wih_b : Wih_f;
  const float* bias = dir ? b_b  : b_f;

  int tid = threadIdx.x;
  if (tid < 64) tok[tid] = inp[tid * T_LEN + t];   // inp[b][t]
  __syncthreads();

  int lr = tid >> 2;         // staging row 0..63
  int kp = tid & 3;          // staging k-part
  int tx = tid & 15, ty = tid >> 4;
  float acc[4][4] = {{0.f}};

  for (int k0 = 0; k0 < 256; k0 += 32) {
    const float* ap = emb + (size_t)tok[lr] * EMBD + k0 + kp * 8;
    const float* bp = W   + (size_t)(wr0 + lr) * EMBD + k0 + kp * 8;
    float4 a0 = *(const float4*)ap;
    float4 a1 = *(const float4*)(ap + 4);
    float4 q0 = *(const float4*)bp;
    float4 q1 = *(const float4*)(bp + 4);
    int kk = kp * 8;
    As[kk+0][lr]=a0.x; As[kk+1][lr]=a0.y; As[kk+2][lr]=a0.z; As[kk+3][lr]=a0.w;
    As[kk+4][lr]=a1.x; As[kk+5][lr]=a1.y; As[kk+6][lr]=a1.z; As[kk+7][lr]=a1.w;
    Bs[kk+0][lr]=q0.x; Bs[kk+1][lr]=q0.y; Bs[kk+2][lr]=q0.z; Bs[kk+3][lr]=q0.w;
    Bs[kk+4][lr]=q1.x; Bs[kk+5][lr]=q1.y; Bs[kk+6][lr]=q1.z; Bs[kk+7][lr]=q1.w;
    __syncthreads();
    #pragma unroll
    for (int k = 0; k < 32; ++k) {
      float4 av = *(const float4*)&As[k][ty*4];
      float4 bv = *(const float4*)&Bs[k][tx*4];
      acc[0][0]+=av.x*bv.x; acc[0][1]+=av.x*bv.y; acc[0][2]+=av.x*bv.z; acc[0][3]+=av.x*bv.w;
      acc[1][0]+=av.y*bv.x; acc[1][1]+=av.y*bv.y; acc[1][2]+=av.y*bv.z; acc[1][3]+=av.y*bv.w;
      acc[2][0]+=av.z*bv.x; acc[2][1]+=av.z*bv.y; acc[2][2]+=av.z*bv.z; acc[2][3]+=av.z*bv.w;
      acc[3][0]+=av.w*bv.x; acc[3][1]+=av.w*bv.y; acc[3][2]+=av.w*bv.z; acc[3][3]+=av.w*bv.w;
    }
    __syncthreads();
  }
  float bj0 = bias[wr0 + tx*4 + 0];
  float bj1 = bias[wr0 + tx*4 + 1];
  float bj2 = bias[wr0 + tx*4 + 2];
  float bj3 = bias[wr0 + tx*4 + 3];
  #pragma unroll
  for (int i = 0; i < 4; ++i) {
    int b_idx = ty*4 + i;
    size_t off = ((size_t)(dir*T_LEN + t)*NB + b_idx)*G4 + wr0 + tx*4;
    ushort4 v;
    v.x = f2bf(acc[i][0] + bj0);
    v.y = f2bf(acc[i][1] + bj1);
    v.z = f2bf(acc[i][2] + bj2);
    v.w = f2bf(acc[i][3] + bj3);
    *(ushort4*)(xW + off) = v;
  }
}

// ---------------- K2: LSTM recurrence, one block per (dir, batch row) ----------------
// thread == hidden channel; weights streamed bf16 from L2 (L1 catches 3/4 of requests);
// h kept in LDS (double-buffered, 1 sync/step); c in a register. mask==1 inside [0,len).
extern "C" __global__ __launch_bounds__(256) void k2_lstm(
    const int* __restrict__ mask, const u16* __restrict__ whh,
    const u16* __restrict__ xW, u16* __restrict__ h_out)
{
  __shared__ __align__(16) float h_lds[2][256];
  __shared__ int len_sh;

  int blk = blockIdx.x;          // 0..127
  int dir = blk >> 6;
  int row = blk & 63;
  int tid = threadIdx.x;

  int s_ = mask[row*T_LEN + tid] + mask[row*T_LEN + 256 + tid];
  #pragma unroll
  for (int off = 32; off; off >>= 1) s_ += __shfl_down(s_, off);
  if (tid == 0) len_sh = 0;
  __syncthreads();
  if ((tid & 63) == 0) atomicAdd(&len_sh, s_);
  h_lds[0][tid] = 0.f;
  h_lds[1][tid] = 0.f;
  __syncthreads();
  int len = len_sh;

  float c = 0.f;
  const u16* wb  = whh + (size_t)dir * 262144;          // [1024][256] bf16
  const u16* wri = wb + (size_t)(tid       ) * 256;
  const u16* wrf = wb + (size_t)(tid +  256) * 256;
  const u16* wrg = wb + (size_t)(tid +  512) * 256;
  const u16* wro = wb + (size_t)(tid +  768) * 256;

  for (int s = 0; s < len; ++s) {
    int t = dir ? (len - 1 - s) : s;                    // backward dir runs reversed
    const float* h = h_lds[s & 1];
    const u16* xwp = xW + ((size_t)(dir*T_LEN + t)*NB + row)*G4;
    float xi = bf2f(xwp[      tid]);
    float xf = bf2f(xwp[256 + tid]);
    float xg = bf2f(xwp[512 + tid]);
    float xo = bf2f(xwp[768 + tid]);
    float di = 0.f, df = 0.f, dg = 0.f, dco = 0.f;
    #pragma unroll 4
    for (int k = 0; k < 256; k += 8) {
      float4 h0 = *(const float4*)(h + k);
      float4 h1 = *(const float4*)(h + k + 4);
      uint4 wi = *(const uint4*)(wri + k);
      uint4 wf = *(const uint4*)(wrf + k);
      uint4 wg = *(const uint4*)(wrg + k);
      uint4 wo = *(const uint4*)(wro + k);
      di += bf_lo(wi.x)*h0.x + bf_hi(wi.x)*h0.y + bf_lo(wi.y)*h0.z + bf_hi(wi.y)*h0.w
          + bf_lo(wi.z)*h1.x + bf_hi(wi.z)*h1.y + bf_lo(wi.w)*h1.z + bf_hi(wi.w)*h1.w;
      df += bf_lo(wf.x)*h0.x + bf_hi(wf.x)*h0.y + bf_lo(wf.y)*h0.z + bf_hi(wf.y)*h0.w
          + bf_lo(wf.z)*h1.x + bf_hi(wf.z)*h1.y + bf_lo(wf.w)*h1.z + bf_hi(wf.w)*h1.w;
      dg += bf_lo(wg.x)*h0.x + bf_hi(wg.x)*h0.y + bf_lo(wg.y)*h0.z + bf_hi(wg.y)*h0.w
          + bf_lo(wg.z)*h1.x + bf_hi(wg.z)*h1.y + bf_lo(wg.w)*h1.z + bf_hi(wg.w)*h1.w;
      dco+= bf_lo(wo.x)*h0.x + bf_hi(wo.x)*h0.y + bf_lo(wo.y)*h0.z + bf_hi(wo.y)*h0.w
          + bf_lo(wo.z)*h1.x + bf_hi(wo.z)*h1.y + bf_lo(wo.w)*h1.z + bf_hi(wo.w)*h1.w;
    }
    float ig = sigm(xi + di);
    float fg = sigm(xf + df);
    float gg = tanhfast(xg + dg);
    float og = sigm(xo + dco);
    float cn = fg * c + ig * gg;
    float hn = og * tanhfast(cn);
    c = cn;
    h_lds[(s & 1) ^ 1][tid] = hn;
    h_out[((size_t)(dir*T_LEN + t)*NB + row)*HD + tid] = f2bf(hn);
    __syncthreads();
  }
}

// ---------------- K4: h_tag + CRF forward + gold score, one block per batch row ----------------
extern "C" __global__ __launch_bounds__(256) void k4_crf(
    const int* __restrict__ mask, const int* __restrict__ gold,
    const u16* __restrict__ h_out, const float* __restrict__ W_tag,
    const float* __restrict__ b_tag, const float* __restrict__ trans,
    float* __restrict__ out)
{
  __shared__ __align__(16) u16 w_lds[32][516];   // bf16 W_tag, pad 516 (b64-aligned, 4-way max)
  __shared__ float trans_s[32][33];              // +1 pad -> conflict-free row reads
  __shared__ float bt_s[32];
  __shared__ __align__(16) u16 h_s[512];         // [h_f | h_b]
  __shared__ float part[8][32];
  __shared__ float ht[32];
  __shared__ float score[32];
  __shared__ int len_sh;

  int b = blockIdx.x;
  int tid = threadIdx.x;

  for (int i = tid; i < 32*512; i += 256) w_lds[i >> 9][i & 511] = f2bf(W_tag[i]);
  for (int i = tid; i < 1024;  i += 256) trans_s[i >> 5][i & 31] = trans[i];
  if (tid < 32) { bt_s[tid] = b_tag[tid]; score[tid] = (tid == STOPID) ? 0.f : -10000.f; }
  int s_ = mask[b*T_LEN + tid] + mask[b*T_LEN + 256 + tid];
  #pragma unroll
  for (int off = 32; off; off >>= 1) s_ += __shfl_down(s_, off);
  if (tid == 0) len_sh = 0;
  __syncthreads();
  if ((tid & 63) == 0) atomicAdd(&len_sh, s_);
  __syncthreads();
  int len = len_sh;

  int j = tid & 31, q = tid >> 5;
  float gscore = 0.f;
  int g_cur = gold[b*T_LEN];

  for (int t = 0; t < len; ++t) {
    if (tid < 64) {   // stage h_f|h_b for (t,b): 512 bf16
      int d = tid >> 5, seg = tid & 31;
      const u16* src = h_out + ((size_t)(d*T_LEN + t)*NB + b)*HD + seg*8;
      *(uint4*)&h_s[d*256 + seg*8] = *(const uint4*)src;
    }
    __syncthreads();
    // h_tag dot: 32 tags x 8 k-segments
    float dsum = 0.f;
    const u16* wrow = &w_lds[j][q*64];
    const u16* hrow = &h_s[q*64];
    #pragma unroll
    for (int k = 0; k < 64; k += 4) {
      uint2 wv = *(const uint2*)(wrow + k);
      uint2 hv = *(const uint2*)(hrow + k);
      dsum += bf_lo(wv.x)*bf_lo(hv.x) + bf_hi(wv.x)*bf_hi(hv.x)
            + bf_lo(wv.y)*bf_lo(hv.y) + bf_hi(wv.y)*bf_hi(hv.y);
    }
    part[q][j] = dsum;
    __syncthreads();
    if (tid < 32) {
      float e = bt_s[tid];
      #pragma unroll
      for (int qq = 0; qq < 8; ++qq) e += part[qq][tid];
      ht[tid] = e;                                  // mask==1 for t<len
    }
    __syncthreads();
    float ns = 0.f;
    if (tid < 32) {                                 // score'[k] = ht[k] + lse_j(score[j]+trans[k][j])
      float m = -3.0e38f;
      #pragma unroll
      for (int p = 0; p < 32; ++p) { float v = score[p] + trans_s[tid][p]; m = fmaxf(m, v); }
      float se = 0.f;
      #pragma unroll
      for (int p = 0; p < 32; ++p) { float v = score[p] + trans_s[tid][p]; se += __expf(v - m); }
      ns = ht[tid] + m + __logf(se);
    }
    __syncthreads();
    if (tid < 32) score[tid] = ns;
    if (tid == 0 && t < T_LEN - 1) {                // gold-path emit + transition
      int g_next = gold[b*T_LEN + t + 1];
      gscore += ht[g_next] + trans_s[g_next][g_cur];
      g_cur = g_next;
    }
    __syncthreads();
  }
  if (tid == 0) {
    float m = -3.0e38f;
    for (int p = 0; p < 32; ++p) { float v = score[p] + trans_s[STOPID][p]; m = fmaxf(m, v); }
    float se = 0.f;
    for (int p = 0; p < 32; ++p) { float v = score[p] + trans_s[STOPID][p]; se += __expf(v - m); }
    float Z = m + __logf(se);
    int g_last = gold[b*T_LEN + len - 1];
    out[b] = Z - (gscore + trans_s[STOPID][g_last]);
  }
}

extern "C" void kernel_launch(void* const* d_in, const int* in_sizes, int n_in,
                              void* d_out, int out_size, void* d_ws, size_t ws_size,
                              hipStream_t stream)
{
  const int*   inp   = (const int*)  d_in[0];
  const int*   gold  = (const int*)  d_in[1];
  const int*   mask  = (const int*)  d_in[2];
  const float* emb   = (const float*)d_in[3];
  const float* Wih_f = (const float*)d_in[4];
  const float* Whh_f = (const float*)d_in[5];
  const float* b_f   = (const float*)d_in[6];
  const float* Wih_b = (const float*)d_in[7];
  const float* Whh_b = (const float*)d_in[8];
  const float* b_b   = (const float*)d_in[9];
  const float* W_tag = (const float*)d_in[10];
  const float* b_tag = (const float*)d_in[11];
  const float* trans = (const float*)d_in[12];
  float* out = (float*)d_out;

  char* ws = (char*)d_ws;
  u16* whh_bf = (u16*)ws;                                      // 1 MiB   (2x1024x256 bf16)
  u16* xW     = (u16*)(ws + (1u<<20));                         // 128 MiB (2x512x64x1024 bf16)
  u16* h_outp = (u16*)(ws + (1u<<20) + 134217728u);            // 32 MiB  (2x512x64x256 bf16)

  hipLaunchKernelGGL(k0_cvt,  dim3(1024),    dim3(256), 0, stream, Whh_f, Whh_b, whh_bf);
  hipLaunchKernelGGL(k1_proj, dim3(512, 32), dim3(256), 0, stream, inp, emb, Wih_f, Wih_b, b_f, b_b, xW);
  hipLaunchKernelGGL(k2_lstm, dim3(128),     dim3(256), 0, stream, mask, whh_bf, xW, h_outp);
  hipLaunchKernelGGL(k4_crf,  dim3(64),      dim3(256), 0, stream, mask, gold, h_outp, W_tag, b_tag, trans, out);
}

// Round 2
// 4106.779 us; speedup vs baseline: 2.1662x; 2.1662x over previous
//
#include <hip/hip_runtime.h>
#include <stdint.h>

#define T_LEN 512
#define NB 64
#define STOPID 30

typedef unsigned short u16;
typedef unsigned int u32;
typedef short bf8 __attribute__((ext_vector_type(8)));
typedef float f32x4 __attribute__((ext_vector_type(4)));

__device__ __forceinline__ float bf_lo(u32 u){ return __uint_as_float(u << 16); }
__device__ __forceinline__ float bf_hi(u32 u){ return __uint_as_float(u & 0xFFFF0000u); }
__device__ __forceinline__ float bf2f(u16 v){ return __uint_as_float(((u32)v) << 16); }
__device__ __forceinline__ u16 f2bf(float f){
  u32 u = __float_as_uint(f);
  return (u16)((u + 0x7FFFu + ((u >> 16) & 1u)) >> 16);
}
__device__ __forceinline__ float sigm(float x){ return 1.0f/(1.0f + __expf(-x)); }
__device__ __forceinline__ float tanhfast(float x){ return 1.0f - 2.0f/(1.0f + __expf(2.0f*x)); }

// ---------------- K0: fp32 -> bf16 weight conversion (Whh + Wih, both dirs) ----------------
extern "C" __global__ __launch_bounds__(256) void k0_cvt(
    const float* __restrict__ whf, const float* __restrict__ whb,
    const float* __restrict__ wif, const float* __restrict__ wib,
    u16* __restrict__ whh_bf, u16* __restrict__ wih_bf)
{
  int i = blockIdx.x * 256 + threadIdx.x;   // grid 1024 -> 262144
  whh_bf[i]          = f2bf(whf[i]);
  whh_bf[262144 + i] = f2bf(whb[i]);
  wih_bf[i]          = f2bf(wif[i]);
  wih_bf[262144 + i] = f2bf(wib[i]);
}

// ---------------- K_init: zero h_init + barrier counters; compute lengths ----------------
extern "C" __global__ __launch_bounds__(256) void k_init(
    const int* __restrict__ mask, u32* __restrict__ h_init_u32,
    u32* __restrict__ cnt, int* __restrict__ lenv)
{
  int bid = blockIdx.x, tid = threadIdx.x;
  if (bid < 32) {
    h_init_u32[bid*256 + tid] = 0u;           // 8192 u32 = 32KB zeros (bf16 zeros)
  } else if (bid == 32) {
    if (tid < 256) { cnt[tid] = 0u; cnt[256+tid] = 0u; cnt[512+tid] = 0u; cnt[768+tid] = 0u; }
  } else {
    if (tid < 64) lenv[tid] = 0;
    __syncthreads();
    int r = tid >> 2, p = tid & 3;
    int s = 0;
    for (int k = 0; k < 128; ++k) s += mask[r*T_LEN + p*128 + k];
    atomicAdd(&lenv[r], s);
  }
}

// ---------------- K1: xW[dir][t][gate][row] = bf16( emb[inp] @ Wih^T + b ) via MFMA ----------------
// grid (512, 32) x 256 thr. Each wave: 16 rows x 64 gates, K=256. y -> (dir, 64-gate block).
extern "C" __global__ __launch_bounds__(256) void k1_proj(
    const int* __restrict__ inp, const float* __restrict__ emb,
    const u16* __restrict__ wih, const float* __restrict__ b_f,
    const float* __restrict__ b_b, u16* __restrict__ xW)
{
  int t  = blockIdx.x;
  int gb = blockIdx.y;              // 0..31
  int dir  = gb >> 4;
  int nblk = gb & 15;               // 64-gate block within dir
  int w    = threadIdx.x >> 6;      // wave id = M-tile (rows 16w..16w+16)
  int lane = threadIdx.x & 63;
  int lr = lane & 15, q = lane >> 4;
  int r  = w*16 + lr;

  int tok = inp[r*T_LEN + t];
  const float* arow = emb + (size_t)tok * 256;
  bf8 af[8];
  #pragma unroll
  for (int kt = 0; kt < 8; ++kt) {
    float4 f0 = *(const float4*)(arow + kt*32 + q*8);
    float4 f1 = *(const float4*)(arow + kt*32 + q*8 + 4);
    bf8 v;
    v[0]=(short)f2bf(f0.x); v[1]=(short)f2bf(f0.y); v[2]=(short)f2bf(f0.z); v[3]=(short)f2bf(f0.w);
    v[4]=(short)f2bf(f1.x); v[5]=(short)f2bf(f1.y); v[6]=(short)f2bf(f1.z); v[7]=(short)f2bf(f1.w);
    af[kt] = v;
  }

  const u16* wbase = wih + (size_t)dir*262144 + (size_t)nblk*64*256;
  f32x4 acc[4];
  #pragma unroll
  for (int n = 0; n < 4; ++n) { acc[n][0]=0.f; acc[n][1]=0.f; acc[n][2]=0.f; acc[n][3]=0.f; }
  #pragma unroll
  for (int n = 0; n < 4; ++n) {
    #pragma unroll
    for (int kt = 0; kt < 8; ++kt) {
      bf8 b = *(const bf8*)(wbase + (size_t)(n*16 + lr)*256 + kt*32 + q*8);
      acc[n] = __builtin_amdgcn_mfma_f32_16x16x32_bf16(af[kt], b, acc[n], 0, 0, 0);
    }
  }

  const float* bias = dir ? b_b : b_f;
  u16* xp = xW + ((size_t)(dir*T_LEN + t)*1024 + nblk*64)*64;
  #pragma unroll
  for (int n = 0; n < 4; ++n) {
    float bv = bias[nblk*64 + n*16 + lr];
    ushort4 st;
    st.x = f2bf(acc[n][0] + bv);
    st.y = f2bf(acc[n][1] + bv);
    st.z = f2bf(acc[n][2] + bv);
    st.w = f2bf(acc[n][3] + bv);
    *(ushort4*)(xp + (size_t)(n*16 + lr)*64 + w*16 + q*4) = st;
  }
}

// ---------------- K2: LSTM recurrence, 64 persistent waves per direction ----------------
// Wave u owns rows [16(u&3),+16) x channels [16(u>>2),+16) (all 4 gates). Whh fragments live
// in registers for all 512 steps (zero weight traffic). Per-step all-to-all h exchange via
// global h_out + device-scope release/acquire barrier counter. xW(t+1) prefetched pre-spin.
extern "C" __global__ __launch_bounds__(64) void k2_lstm(
    const u16* __restrict__ whh, const u16* __restrict__ xW,
    const int* __restrict__ lenv, const u16* __restrict__ h_init,
    u16* __restrict__ h_out, u32* __restrict__ cnt)
{
  int bid = blockIdx.x;             // 0..127
  int dir = bid >> 6;
  int u   = bid & 63;
  int mt = u & 3, nb = u >> 2;
  int lane = threadIdx.x;
  int lr = lane & 15, q = lane >> 4;
  int r0 = mt*16;
  int c0 = nb*16;

  // Whh B-fragments: 4 gates x 8 K-steps, register-resident (128 VGPRs)
  bf8 bw[4][8];
  const u16* wbase = whh + (size_t)dir*262144;
  #pragma unroll
  for (int g = 0; g < 4; ++g)
    #pragma unroll
    for (int kt = 0; kt < 8; ++kt)
      bw[g][kt] = *(const bf8*)(wbase + (size_t)(g*256 + c0 + lr)*256 + kt*32 + q*8);

  float cst0=0.f,cst1=0.f,cst2=0.f,cst3=0.f;
  float hst0=0.f,hst1=0.f,hst2=0.f,hst3=0.f;
  int4 ln = *(const int4*)(lenv + r0 + q*4);

  u32* mycnt = cnt + dir*512;
  int t = dir ? (T_LEN-1) : 0;
  ushort4 xv[4];
  {
    const u16* xp = xW + (size_t)(dir*T_LEN + t)*1024*64;
    #pragma unroll
    for (int g = 0; g < 4; ++g)
      xv[g] = *(const ushort4*)(xp + (size_t)(g*256 + c0 + lr)*64 + r0 + q*4);
  }
  const u16* hprev = h_init;

  for (int s = 0; s < T_LEN; ++s) {
    // A fragments: h(t_prev) rows r0..r0+16
    bf8 af[8];
    #pragma unroll
    for (int kt = 0; kt < 8; ++kt)
      af[kt] = *(const bf8*)(hprev + (size_t)(r0 + lr)*256 + kt*32 + q*8);

    f32x4 a0,a1,a2,a3;
    a0[0]=0.f;a0[1]=0.f;a0[2]=0.f;a0[3]=0.f; a1=a0; a2=a0; a3=a0;
    #pragma unroll
    for (int kt = 0; kt < 8; ++kt) {
      a0 = __builtin_amdgcn_mfma_f32_16x16x32_bf16(af[kt], bw[0][kt], a0, 0, 0, 0);
      a1 = __builtin_amdgcn_mfma_f32_16x16x32_bf16(af[kt], bw[1][kt], a1, 0, 0, 0);
      a2 = __builtin_amdgcn_mfma_f32_16x16x32_bf16(af[kt], bw[2][kt], a2, 0, 0, 0);
      a3 = __builtin_amdgcn_mfma_f32_16x16x32_bf16(af[kt], bw[3][kt], a3, 0, 0, 0);
    }

    u16* hop = h_out + (size_t)(dir*T_LEN + t)*NB*256;
    #define EPI(J, COMP, CST, HST, LNJ) { \
      float ip = a0[J] + bf2f(xv[0].COMP); \
      float fp = a1[J] + bf2f(xv[1].COMP); \
      float gp = a2[J] + bf2f(xv[2].COMP); \
      float op = a3[J] + bf2f(xv[3].COMP); \
      float cn = sigm(fp)*CST + sigm(ip)*tanhfast(gp); \
      float hn = sigm(op)*tanhfast(cn); \
      bool mk = (t < LNJ); \
      CST = mk ? cn : CST; HST = mk ? hn : HST; \
      hop[(size_t)(r0 + q*4 + J)*256 + c0 + lr] = f2bf(HST); }
    EPI(0, x, cst0, hst0, ln.x)
    EPI(1, y, cst1, hst1, ln.y)
    EPI(2, z, cst2, hst2, ln.z)
    EPI(3, w, cst3, hst3, ln.w)
    #undef EPI

    if (s < T_LEN-1) {
      // arrive (release: drains the h stores, makes them agent-visible)
      if (lane == 0)
        __hip_atomic_fetch_add(&mycnt[s], 1u, __ATOMIC_RELEASE, __HIP_MEMORY_SCOPE_AGENT);
      // prefetch xW for next t while waiting
      int tn = dir ? (T_LEN-2 - s) : (s + 1);
      const u16* xp = xW + (size_t)(dir*T_LEN + tn)*1024*64;
      #pragma unroll
      for (int g = 0; g < 4; ++g)
        xv[g] = *(const ushort4*)(xp + (size_t)(g*256 + c0 + lr)*64 + r0 + q*4);
      // wait for all 64 waves of this direction
      while (__hip_atomic_load(&mycnt[s], __ATOMIC_ACQUIRE, __HIP_MEMORY_SCOPE_AGENT) < 64u) {}
      hprev = h_out + (size_t)(dir*T_LEN + t)*NB*256;
      t = tn;
    }
  }
}

// ---------------- K4: h_tag + CRF forward + gold score, one block per batch row ----------------
extern "C" __global__ __launch_bounds__(256) void k4_crf(
    const int* __restrict__ mask, const int* __restrict__ gold,
    const u16* __restrict__ h_out, const float* __restrict__ W_tag,
    const float* __restrict__ b_tag, const float* __restrict__ trans,
    float* __restrict__ out)
{
  __shared__ __align__(16) u16 w_lds[32][516];
  __shared__ float trans_s[32][33];
  __shared__ float bt_s[32];
  __shared__ __align__(16) u16 h_s[512];
  __shared__ float part[8][32];
  __shared__ float ht[32];
  __shared__ float score[32];
  __shared__ int len_sh;

  int b = blockIdx.x;
  int tid = threadIdx.x;

  for (int i = tid; i < 32*512; i += 256) w_lds[i >> 9][i & 511] = f2bf(W_tag[i]);
  for (int i = tid; i < 1024;  i += 256) trans_s[i >> 5][i & 31] = trans[i];
  if (tid < 32) { bt_s[tid] = b_tag[tid]; score[tid] = (tid == STOPID) ? 0.f : -10000.f; }
  int s_ = mask[b*T_LEN + tid] + mask[b*T_LEN + 256 + tid];
  #pragma unroll
  for (int off = 32; off; off >>= 1) s_ += __shfl_down(s_, off);
  if (tid == 0) len_sh = 0;
  __syncthreads();
  if ((tid & 63) == 0) atomicAdd(&len_sh, s_);
  __syncthreads();
  int len = len_sh;

  int j = tid & 31, q = tid >> 5;
  float gscore = 0.f;
  int g_cur = gold[b*T_LEN];

  for (int t = 0; t < len; ++t) {
    if (tid < 64) {
      int d = tid >> 5, seg = tid & 31;
      const u16* src = h_out + ((size_t)(d*T_LEN + t)*NB + b)*256 + seg*8;
      *(uint4*)&h_s[d*256 + seg*8] = *(const uint4*)src;
    }
    __syncthreads();
    float dsum = 0.f;
    const u16* wrow = &w_lds[j][q*64];
    const u16* hrow = &h_s[q*64];
    #pragma unroll
    for (int k = 0; k < 64; k += 4) {
      uint2 wv = *(const uint2*)(wrow + k);
      uint2 hv = *(const uint2*)(hrow + k);
      dsum += bf_lo(wv.x)*bf_lo(hv.x) + bf_hi(wv.x)*bf_hi(hv.x)
            + bf_lo(wv.y)*bf_lo(hv.y) + bf_hi(wv.y)*bf_hi(hv.y);
    }
    part[q][j] = dsum;
    __syncthreads();
    if (tid < 32) {
      float e = bt_s[tid];
      #pragma unroll
      for (int qq = 0; qq < 8; ++qq) e += part[qq][tid];
      ht[tid] = e;
    }
    __syncthreads();
    float ns = 0.f;
    if (tid < 32) {
      float m = -3.0e38f;
      #pragma unroll
      for (int p = 0; p < 32; ++p) { float v = score[p] + trans_s[tid][p]; m = fmaxf(m, v); }
      float se = 0.f;
      #pragma unroll
      for (int p = 0; p < 32; ++p) { float v = score[p] + trans_s[tid][p]; se += __expf(v - m); }
      ns = ht[tid] + m + __logf(se);
    }
    __syncthreads();
    if (tid < 32) score[tid] = ns;
    if (tid == 0 && t < T_LEN - 1) {
      int g_next = gold[b*T_LEN + t + 1];
      gscore += ht[g_next] + trans_s[g_next][g_cur];
      g_cur = g_next;
    }
    __syncthreads();
  }
  if (tid == 0) {
    float m = -3.0e38f;
    for (int p = 0; p < 32; ++p) { float v = score[p] + trans_s[STOPID][p]; m = fmaxf(m, v); }
    float se = 0.f;
    for (int p = 0; p < 32; ++p) { float v = score[p] + trans_s[STOPID][p]; se += __expf(v - m); }
    float Z = m + __logf(se);
    int g_last = gold[b*T_LEN + len - 1];
    out[b] = Z - (gscore + trans_s[STOPID][g_last]);
  }
}

extern "C" void kernel_launch(void* const* d_in, const int* in_sizes, int n_in,
                              void* d_out, int out_size, void* d_ws, size_t ws_size,
                              hipStream_t stream)
{
  const int*   inp   = (const int*)  d_in[0];
  const int*   gold  = (const int*)  d_in[1];
  const int*   mask  = (const int*)  d_in[2];
  const float* emb   = (const float*)d_in[3];
  const float* Wih_f = (const float*)d_in[4];
  const float* Whh_f = (const float*)d_in[5];
  const float* Wih_b = (const float*)d_in[7];
  const float* Whh_b = (const float*)d_in[8];
  const float* b_f   = (const float*)d_in[6];
  const float* b_b   = (const float*)d_in[9];
  const float* W_tag = (const float*)d_in[10];
  const float* b_tag = (const float*)d_in[11];
  const float* trans = (const float*)d_in[12];
  float* out = (float*)d_out;

  char* ws = (char*)d_ws;
  u16* whh_bf = (u16*)(ws + 0);                 // 1 MiB
  u16* wih_bf = (u16*)(ws + 1048576);           // 1 MiB
  u16* xW     = (u16*)(ws + 2097152);           // 128 MiB [dir][t][gate][row]
  u16* h_outp = (u16*)(ws + 136314880);         // 32 MiB  [dir][t][row][256]
  u16* h_init = (u16*)(ws + 169869312);         // 32 KiB zeros
  u32* cntp   = (u32*)(ws + 169902080);         // 4 KiB barrier counters
  int* lenv   = (int*)(ws + 169906176);         // 256 B

  hipLaunchKernelGGL(k0_cvt,  dim3(1024),     dim3(256), 0, stream,
                     Whh_f, Whh_b, Wih_f, Wih_b, whh_bf, wih_bf);
  hipLaunchKernelGGL(k_init,  dim3(34),       dim3(256), 0, stream,
                     mask, (u32*)h_init, cntp, lenv);
  hipLaunchKernelGGL(k1_proj, dim3(512, 32),  dim3(256), 0, stream,
                     inp, emb, wih_bf, b_f, b_b, xW);
  hipLaunchKernelGGL(k2_lstm, dim3(128),      dim3(64),  0, stream,
                     whh_bf, xW, lenv, h_init, h_outp, cntp);
  hipLaunchKernelGGL(k4_crf,  dim3(64),       dim3(256), 0, stream,
                     mask, gold, h_outp, W_tag, b_tag, trans, out);
}